// Round 5
// baseline (509.330 us; speedup 1.0000x reference)
//
#include <hip/hip_runtime.h>
#include <math.h>

#define NBINS 15
#define NCLS 100
#define ECE_EPS 1e-5f

// Workspace layout (zeroed by hipMemsetAsync each launch):
//   g_cnt[100] : int   argmax histogram
//   g_acc[100] : float sum of (pred==label) per argmax class (~0, kept faithful)
//   g_done[1]  : int   completed-block counter (fused finalization)

// One wave (64-thread block) per 64-row chunk, single-buffered LDS staging via
// global_load_lds (25 x 1KB coalesced instrs). Lane L processes row L from LDS;
// read order rotated by (L>>3) -> the 8 lanes sharing a bank-base cover all 32
// banks -> conflict-free ds_read_b128. 26.6 KB LDS -> 6 blocks/CU staggered,
// which keeps ~1.5 waves/CU in their staging phase at all times (collective
// pipelining; measured better than explicit double-buffer in R4).
// Last block to finish folds the 100-class histogram into the 15-bin sums and
// writes the final scalar (saves one dispatch + launch gap).
__global__ __launch_bounds__(64) void ece_hist(const float* __restrict__ logits,
                                               const int* __restrict__ labels,
                                               int* __restrict__ g_cnt,
                                               float* __restrict__ g_acc,
                                               int* __restrict__ g_done,
                                               float* __restrict__ out,
                                               int n_rows) {
    __shared__ float s_rows[64 * NCLS];   // 25.6 KB staging
    __shared__ int   s_cnt[NCLS];
    __shared__ float s_accs[NCLS];
    __shared__ float s_bins[3 * NBINS];

    const int lane = threadIdx.x;          // single wave per block
    #pragma unroll
    for (int i = lane; i < NCLS; i += 64) { s_cnt[i] = 0; s_accs[i] = 0.0f; }

    const int n_chunks = n_rows >> 6;
    const int rot = (lane >> 3) & 7;       // bank-spread rotation

    for (int chunk = blockIdx.x; chunk < n_chunks; chunk += gridDim.x) {
        const float* gbase = logits + (size_t)chunk * (64 * NCLS);
        #pragma unroll
        for (int j = 0; j < 25; ++j) {
            __builtin_amdgcn_global_load_lds(
                (const __attribute__((address_space(1))) void*)(gbase + (size_t)(j * 64 + lane) * 4),
                (__attribute__((address_space(3))) void*)(&s_rows[j * 256]),
                16, 0, 0);
        }
        const int lab = labels[chunk * 64 + lane];
        __builtin_amdgcn_s_waitcnt(0);     // drain vmcnt: LDS staging complete

        const float4* __restrict__ rp = (const float4*)&s_rows[lane * NCLS];

        // pass 1: max/argmax (rotated order; explicit lowest-index tie-break)
        float m = -INFINITY; int mi = 1 << 30;
        #pragma unroll
        for (int j = 0; j < 25; ++j) {
            int jj = j + rot; jj -= (jj >= 25) ? 25 : 0;
            const float4 x = rp[jj];
            const int base = 4 * jj;
            if (x.x > m || (x.x == m && base     < mi)) { m = x.x; mi = base;     }
            if (x.y > m || (x.y == m && base + 1 < mi)) { m = x.y; mi = base + 1; }
            if (x.z > m || (x.z == m && base + 2 < mi)) { m = x.z; mi = base + 2; }
            if (x.w > m || (x.w == m && base + 3 < mi)) { m = x.w; mi = base + 3; }
        }
        // pass 2: sum exp(x - m)
        float s0 = 0.0f, s1 = 0.0f, s2 = 0.0f, s3 = 0.0f;
        #pragma unroll
        for (int j = 0; j < 25; ++j) {
            int jj = j + rot; jj -= (jj >= 25) ? 25 : 0;
            const float4 x = rp[jj];
            s0 += __expf(x.x - m);
            s1 += __expf(x.y - m);
            s2 += __expf(x.z - m);
            s3 += __expf(x.w - m);
        }
        const float pred = -__logf((s0 + s1) + (s2 + s3));   // max of log_softmax

        atomicAdd(&s_cnt[mi], 1);
        if (pred == (float)lab) atomicAdd(&s_accs[mi], 1.0f);  // faithful; ~never taken
    }

    // tail rows (n_rows % 64), block 0 only
    const int tail_start = n_chunks << 6;
    if (blockIdx.x == 0 && tail_start + lane < n_rows) {
        const float* row = logits + (size_t)(tail_start + lane) * NCLS;
        float m = -INFINITY; int mi = 0;
        for (int c = 0; c < NCLS; ++c) { const float x = row[c]; if (x > m) { m = x; mi = c; } }
        float s = 0.0f;
        for (int c = 0; c < NCLS; ++c) s += __expf(row[c] - m);
        if (-__logf(s) == (float)labels[tail_start + lane]) atomicAdd(&s_accs[mi], 1.0f);
        atomicAdd(&s_cnt[mi], 1);
    }

    // flush block-local histogram (single wave: LDS ops above are in order)
    #pragma unroll
    for (int i = lane; i < NCLS; i += 64) {
        if (s_cnt[i])          atomicAdd(&g_cnt[i], s_cnt[i]);
        if (s_accs[i] != 0.0f) atomicAdd(&g_acc[i], s_accs[i]);
    }

    // ---- fused finalization: last block folds histogram -> ece ----
    __threadfence();                                   // release our adds
    int last = 0;
    if (lane == 0) last = (atomicAdd(g_done, 1) == (int)gridDim.x - 1);
    last = __shfl(last, 0);
    if (!last) return;
    __threadfence();                                   // acquire others' adds

    if (lane < 3 * NBINS) s_bins[lane] = 0.0f;
    for (int c = lane; c < NCLS; c += 64) {
        const float cnt  = (float)__hip_atomic_load(&g_cnt[c], __ATOMIC_ACQUIRE, __HIP_MEMORY_SCOPE_AGENT);
        const float accv = __hip_atomic_load(&g_acc[c], __ATOMIC_ACQUIRE, __HIP_MEMORY_SCOPE_AGENT);
        const float conf = (float)c;
        float diff[NBINS];
        float dm = -INFINITY;
        #pragma unroll
        for (int b = 0; b < NBINS; ++b) {
            const float a = (float)(2 * b + 1) * (1.0f / 30.0f);
            const float d = conf - a;
            diff[b] = -(d * d) * 100.0f;
            dm = fmaxf(dm, diff[b]);
        }
        float es = 0.0f;
        float e[NBINS];
        #pragma unroll
        for (int b = 0; b < NBINS; ++b) { e[b] = __expf(diff[b] - dm); es += e[b]; }
        const float inv = 1.0f / es;
        #pragma unroll
        for (int b = 0; b < NBINS; ++b) {
            const float coeff = e[b] * inv;
            atomicAdd(&s_bins[b],             cnt * coeff);
            atomicAdd(&s_bins[NBINS + b],     conf * cnt * coeff);
            atomicAdd(&s_bins[2 * NBINS + b], accv * coeff);
        }
    }
    // single wave: LDS atomics above complete in program order before these reads
    if (lane == 0) {
        float total = 0.0f;
        #pragma unroll
        for (int b = 0; b < NBINS; ++b) total += fabsf(s_bins[b]);
        const float invw = 1.0f / fmaxf(total, ECE_EPS);
        float ece = 0.0f;
        #pragma unroll
        for (int b = 0; b < NBINS; ++b) {
            const float sc = s_bins[b];
            const float denom = fmaxf(sc, ECE_EPS);
            const float bc = s_bins[NBINS + b] / denom;
            const float ba = s_bins[2 * NBINS + b] / denom;
            const float d  = bc - ba;
            ece += d * d * (sc * invw);
        }
        out[0] = sqrtf(ece);
    }
}

extern "C" void kernel_launch(void* const* d_in, const int* in_sizes, int n_in,
                              void* d_out, int out_size, void* d_ws, size_t ws_size,
                              hipStream_t stream) {
    const float* logits = (const float*)d_in[0];
    const int*   labels = (const int*)d_in[1];
    int*   g_cnt  = (int*)d_ws;
    float* g_acc  = (float*)((char*)d_ws + NCLS * sizeof(int));
    int*   g_done = (int*)((char*)d_ws + NCLS * (sizeof(int) + sizeof(float)));
    float* outp   = (float*)d_out;
    const int n_rows = in_sizes[1];   // labels element count = N

    hipMemsetAsync(d_ws, 0, NCLS * (sizeof(int) + sizeof(float)) + sizeof(int), stream);
    // 26.6 KB LDS -> 6 single-wave blocks/CU; 2048 blocks, N=524288 -> 8192
    // chunks -> exactly 4 chunks/block (balanced; R3's best-measured config).
    ece_hist<<<2048, 64, 0, stream>>>(logits, labels, g_cnt, g_acc, g_done, outp, n_rows);
}

// Round 6
// 425.050 us; speedup vs baseline: 1.1983x; 1.1983x over previous
//
#include <hip/hip_runtime.h>
#include <math.h>

#define NBINS 15
#define NCLS 100
#define ECE_EPS 1e-5f

// Kernel A: one wave (64-thread block) per 64-row chunk, grid-stride.
// Classic staging with REGISTER PREFETCH pipeline:
//   loop top: commit chunk k's 25 float4 (already in VGPRs) to LDS (ds_write_b128,
//   linear layout) -> issue chunk k+1's 25 coalesced global float4 loads (stay in
//   flight, 25.6 KB/wave) -> compute chunk k from LDS.
// Single wave per block: DS ops are wave-ordered, so no barriers anywhere.
// NO device-scope fences (R5 lesson: __threadfence => buffer_wbl2/inv L2
// maintenance storms, 2.5x regression). Finalization is a separate tiny kernel.
// Lane L computes row L; LDS read order rotated by (L>>3) so the 8 lanes sharing
// a bank-group at a given step hit distinct 4-bank groups (conflict-free b128).
__global__ __launch_bounds__(64) void ece_hist(const float* __restrict__ logits,
                                               const int* __restrict__ labels,
                                               int* __restrict__ g_cnt,
                                               float* __restrict__ g_acc,
                                               int n_rows) {
    __shared__ float s_rows[64 * NCLS];   // 25.6 KB staging (linear chunk copy)
    __shared__ int   s_cnt[NCLS];
    __shared__ float s_accs[NCLS];

    const int lane = threadIdx.x;          // 0..63, single wave per block
    #pragma unroll
    for (int i = lane; i < NCLS; i += 64) { s_cnt[i] = 0; s_accs[i] = 0.0f; }

    const int n_chunks = n_rows >> 6;
    const int rot = (lane >> 3) & 7;
    float4* const sw = ((float4*)s_rows) + lane;            // staging write base

    int chunk = blockIdx.x;
    float4 t[25];                                           // prefetch registers
    if (chunk < n_chunks) {
        const float4* gb = (const float4*)(logits + (size_t)chunk * (64 * NCLS));
        #pragma unroll
        for (int j = 0; j < 25; ++j) t[j] = gb[j * 64 + lane];
    }

    while (chunk < n_chunks) {
        // commit staged registers to LDS (linear layout; waits vmcnt per reg use)
        #pragma unroll
        for (int j = 0; j < 25; ++j) sw[j * 64] = t[j];

        const int lab = labels[chunk * 64 + lane];
        const int next = chunk + gridDim.x;
        if (next < n_chunks) {
            const float4* gb = (const float4*)(logits + (size_t)next * (64 * NCLS));
            #pragma unroll
            for (int j = 0; j < 25; ++j) t[j] = gb[j * 64 + lane];  // in flight during compute
        }

        // row `lane` = s_rows[lane*100 .. +99], 16B-aligned
        const float4* __restrict__ rp = (const float4*)&s_rows[lane * NCLS];

        // pass 1: max/argmax (rotated order; explicit lowest-index tie-break)
        float m = -INFINITY; int mi = 1 << 30;
        #pragma unroll
        for (int j = 0; j < 25; ++j) {
            int jj = j + rot; jj -= (jj >= 25) ? 25 : 0;
            const float4 x = rp[jj];
            const int base = 4 * jj;
            if (x.x > m || (x.x == m && base     < mi)) { m = x.x; mi = base;     }
            if (x.y > m || (x.y == m && base + 1 < mi)) { m = x.y; mi = base + 1; }
            if (x.z > m || (x.z == m && base + 2 < mi)) { m = x.z; mi = base + 2; }
            if (x.w > m || (x.w == m && base + 3 < mi)) { m = x.w; mi = base + 3; }
        }
        // pass 2: sum exp(x - m)
        float s0 = 0.0f, s1 = 0.0f, s2 = 0.0f, s3 = 0.0f;
        #pragma unroll
        for (int j = 0; j < 25; ++j) {
            int jj = j + rot; jj -= (jj >= 25) ? 25 : 0;
            const float4 x = rp[jj];
            s0 += __expf(x.x - m);
            s1 += __expf(x.y - m);
            s2 += __expf(x.z - m);
            s3 += __expf(x.w - m);
        }
        const float pred = -__logf((s0 + s1) + (s2 + s3));   // max of log_softmax

        atomicAdd(&s_cnt[mi], 1);
        if (pred == (float)lab) atomicAdd(&s_accs[mi], 1.0f);  // faithful; ~never taken

        chunk = next;
    }

    // tail rows (n_rows % 64 — none at N=524288), block 0 only
    const int tail_start = n_chunks << 6;
    if (blockIdx.x == 0 && tail_start + lane < n_rows) {
        const float* row = logits + (size_t)(tail_start + lane) * NCLS;
        float m = -INFINITY; int mi = 0;
        for (int c = 0; c < NCLS; ++c) { const float x = row[c]; if (x > m) { m = x; mi = c; } }
        float s = 0.0f;
        for (int c = 0; c < NCLS; ++c) s += __expf(row[c] - m);
        if (-__logf(s) == (float)labels[tail_start + lane]) atomicAdd(&s_accs[mi], 1.0f);
        atomicAdd(&s_cnt[mi], 1);
    }

    // flush block-local histogram (single wave: LDS ops above are in order)
    #pragma unroll
    for (int i = lane; i < NCLS; i += 64) {
        if (s_cnt[i])          atomicAdd(&g_cnt[i], s_cnt[i]);
        if (s_accs[i] != 0.0f) atomicAdd(&g_acc[i], s_accs[i]);
    }
}

// Kernel B: fold the 100-entry histogram into the 15-bin sums and the scalar.
// coeff(c,b) = softmax_b( -(c - anchor_b)^2 / 0.01 ), identical math to reference.
__global__ void ece_final(const int* __restrict__ g_cnt,
                          const float* __restrict__ g_acc,
                          float* __restrict__ out) {
    __shared__ float s_bins[3 * NBINS];
    const int tid = threadIdx.x;
    if (tid < 3 * NBINS) s_bins[tid] = 0.0f;
    __syncthreads();

    if (tid < NCLS) {
        const float cnt  = (float)g_cnt[tid];
        const float accv = g_acc[tid];
        const float conf = (float)tid;
        float diff[NBINS];
        float dm = -INFINITY;
        #pragma unroll
        for (int b = 0; b < NBINS; ++b) {
            const float a = (float)(2 * b + 1) * (1.0f / 30.0f);
            const float d = conf - a;
            diff[b] = -(d * d) * 100.0f;
            dm = fmaxf(dm, diff[b]);
        }
        float es = 0.0f;
        float e[NBINS];
        #pragma unroll
        for (int b = 0; b < NBINS; ++b) { e[b] = __expf(diff[b] - dm); es += e[b]; }
        const float inv = 1.0f / es;
        #pragma unroll
        for (int b = 0; b < NBINS; ++b) {
            const float coeff = e[b] * inv;
            atomicAdd(&s_bins[b],             cnt * coeff);
            atomicAdd(&s_bins[NBINS + b],     conf * cnt * coeff);
            atomicAdd(&s_bins[2 * NBINS + b], accv * coeff);
        }
    }
    __syncthreads();

    if (tid == 0) {
        float total = 0.0f;
        #pragma unroll
        for (int b = 0; b < NBINS; ++b) total += fabsf(s_bins[b]);
        const float invw = 1.0f / fmaxf(total, ECE_EPS);
        float ece = 0.0f;
        #pragma unroll
        for (int b = 0; b < NBINS; ++b) {
            const float sc = s_bins[b];
            const float denom = fmaxf(sc, ECE_EPS);
            const float bc = s_bins[NBINS + b] / denom;
            const float ba = s_bins[2 * NBINS + b] / denom;
            const float d  = bc - ba;
            ece += d * d * (sc * invw);
        }
        out[0] = sqrtf(ece);
    }
}

extern "C" void kernel_launch(void* const* d_in, const int* in_sizes, int n_in,
                              void* d_out, int out_size, void* d_ws, size_t ws_size,
                              hipStream_t stream) {
    const float* logits = (const float*)d_in[0];
    const int*   labels = (const int*)d_in[1];
    int*   g_cnt = (int*)d_ws;
    float* g_acc = (float*)((char*)d_ws + NCLS * sizeof(int));
    float* outp  = (float*)d_out;
    const int n_rows = in_sizes[1];   // labels element count = N

    hipMemsetAsync(d_ws, 0, NCLS * (sizeof(int) + sizeof(float)), stream);
    // 26.4 KB LDS -> 6 single-wave blocks/CU; grid 1536 = 6 x 256 CUs so ALL
    // blocks are co-resident (no second-tranche stragglers as with 2048).
    // 8192 chunks -> blocks get 5 or 6 chunks each.
    ece_hist<<<1536, 64, 0, stream>>>(logits, labels, g_cnt, g_acc, n_rows);
    ece_final<<<1, 128, 0, stream>>>(g_cnt, g_acc, outp);
}